// Round 2
// baseline (233.144 us; speedup 1.0000x reference)
//
#include <hip/hip_runtime.h>
#include <hip/hip_fp16.h>
#include <math.h>

#define EPS 1e-20f
#define NPT 256
#define BB  512

// ---- complex float2 helpers ----
__device__ __forceinline__ float2 cadd(float2 a, float2 b){ return make_float2(a.x+b.x, a.y+b.y); }
__device__ __forceinline__ float2 csub(float2 a, float2 b){ return make_float2(a.x-b.x, a.y-b.y); }
__device__ __forceinline__ float2 cmul(float2 a, float2 b){ return make_float2(a.x*b.x - a.y*b.y, a.x*b.y + a.y*b.x); }
__device__ __forceinline__ float2 cmulc(float2 a, float c, float s){ return make_float2(a.x*c - a.y*s, a.x*s + a.y*c); }
__device__ __forceinline__ float2 cmulmi(float2 a){ return make_float2(a.y, -a.x); }   // * (-i)

__device__ __forceinline__ void bfly4(float2& c0, float2& c1, float2& c2, float2& c3) {
    float2 s0 = cadd(c0, c2), s1 = cadd(c1, c3);
    float2 d0 = csub(c0, c2), d1 = cmulmi(csub(c1, c3));
    c0 = cadd(s0, s1); c1 = cadd(d0, d1); c2 = csub(s0, s1); c3 = csub(d0, d1);
}

#define C16_1 0.9238795325112867f
#define S16_1 (-0.3826834323650898f)
#define C16_2 0.7071067811865476f
#define S16_2 (-0.7071067811865476f)
#define C16_3 0.3826834323650898f
#define S16_3 (-0.9238795325112867f)
#define C16_6 (-0.7071067811865476f)
#define S16_6 (-0.7071067811865476f)
#define C16_9 (-0.9238795325112867f)
#define S16_9 0.3826834323650898f

// in-place 16-pt DIF DFT; position p ends up holding frequency r4(p)=4(p&3)+(p>>2)
__device__ __forceinline__ void dft16(float2* x) {
    bfly4(x[0], x[4], x[8], x[12]);
    bfly4(x[1], x[5], x[9], x[13]);
    x[5]  = cmulc(x[5],  C16_1, S16_1);
    x[9]  = cmulc(x[9],  C16_2, S16_2);
    x[13] = cmulc(x[13], C16_3, S16_3);
    bfly4(x[2], x[6], x[10], x[14]);
    x[6]  = cmulc(x[6],  C16_2, S16_2);
    x[10] = cmulmi(x[10]);
    x[14] = cmulc(x[14], C16_6, S16_6);
    bfly4(x[3], x[7], x[11], x[15]);
    x[7]  = cmulc(x[7],  C16_3, S16_3);
    x[11] = cmulc(x[11], C16_6, S16_6);
    x[15] = cmulc(x[15], C16_9, S16_9);
    bfly4(x[0],  x[1],  x[2],  x[3]);
    bfly4(x[4],  x[5],  x[6],  x[7]);
    bfly4(x[8],  x[9],  x[10], x[11]);
    bfly4(x[12], x[13], x[14], x[15]);
}

#define R4C(p) ((((p) & 3) << 2) | ((p) >> 2))

// ---------------- fused kernel: one block per batch ----------------
// 1024 threads = 64 groups of 16 lanes; each group does 4 rows (i values).
// I kept in registers as half2 (I * 2^-12); block-level max; epilogue goes
// through LDS so global stores are coalesced float4 (kills the partial-line
// RMW traffic seen in round 1: WRITE 346MB / FETCH 107MB vs ideal 134MB).
__global__ __launch_bounds__(1024) void k_fused(const float* __restrict__ xin,
                                                float* __restrict__ out) {
    __shared__ float2 El[256];
    __shared__ __align__(16) __half2 T[64 * 328];  // transpose buf; reused as epilogue scratch
    __shared__ float wmax[16];

    const int tid = threadIdx.x;
    const int G   = tid >> 4;         // 0..63
    const int l   = tid & 15;
    const int b   = blockIdx.x;

    // stage raw E (normalization cancels in I/max(I))
    if (tid < 256)
        El[tid] = make_float2(xin[b * 512 + tid], xin[b * 512 + 256 + tid]);
    __syncthreads();

    // twiddle W256^{k1*n2} register powers; k1 = r4(l) (loop-invariant)
    const int k1 = R4C(l);
    float sn, cs;
    __sincosf(-0.024543692606170259f * (float)k1, &sn, &cs);   // -2pi/256 * k1
    const float2 w1 = make_float2(cs, sn);
    const float2 w2 = cmul(w1, w1), w3 = cmul(w2, w1);
    const float2 w4 = cmul(w2, w2), w8 = cmul(w4, w4), w12 = cmul(w8, w4);

    __half2 hreg[4][8];               // I * 2^-12, packed pairs (p2=2q, 2q+1)
    float mx = 0.0f;

    #pragma unroll
    for (int r = 0; r < 4; ++r) {
        const int i = (r << 6) + G;   // row index 0..255

        float2 x[16];
        // ---- gate: x[n1] = E[16n1+l] * E[(16n1+l-i)&255] ----
        #pragma unroll
        for (int n1 = 0; n1 < 16; ++n1) {
            int j = 16 * n1 + l;
            x[n1] = cmul(El[j], El[(j - i) & 255]);
        }

        // ---- inner DFT over n1: x[p1] = Y[k1=r4(p1)][n2=l] ----
        dft16(x);

        // ---- transpose through LDS (half2), b128 writes ----
        {
            float4* wp = (float4*)&T[G * 328 + l * 20];
            #pragma unroll
            for (int q = 0; q < 4; ++q) {
                float4 pk;
                __half2* hp = (__half2*)&pk;
                hp[0] = __floats2half2_rn(x[4 * q + 0].x, x[4 * q + 0].y);
                hp[1] = __floats2half2_rn(x[4 * q + 1].x, x[4 * q + 1].y);
                hp[2] = __floats2half2_rn(x[4 * q + 2].x, x[4 * q + 2].y);
                hp[3] = __floats2half2_rn(x[4 * q + 3].x, x[4 * q + 3].y);
                wp[q] = pk;
            }
        }
        // same wave -> lockstep -> no barrier needed (group reads only its own slice)
        #pragma unroll
        for (int j = 0; j < 16; ++j) {
            x[j] = __half22float2(T[G * 328 + j * 20 + l]);
        }

        // ---- twiddle W256^{k1*n2} ----
        x[1]  = cmul(x[1],  w1);
        x[2]  = cmul(x[2],  w2);
        x[3]  = cmul(x[3],  w3);
        x[4]  = cmul(x[4],  w4);
        x[5]  = cmul(cmul(x[5],  w1), w4);
        x[6]  = cmul(cmul(x[6],  w2), w4);
        x[7]  = cmul(cmul(x[7],  w3), w4);
        x[8]  = cmul(x[8],  w8);
        x[9]  = cmul(cmul(x[9],  w1), w8);
        x[10] = cmul(cmul(x[10], w2), w8);
        x[11] = cmul(cmul(x[11], w3), w8);
        x[12] = cmul(x[12], w12);
        x[13] = cmul(cmul(x[13], w1), w12);
        x[14] = cmul(cmul(x[14], w2), w12);
        x[15] = cmul(cmul(x[15], w3), w12);

        // ---- outer DFT over n2: x[p2] = X[k1 + 16*r4(p2)] ----
        dft16(x);

        // ---- I = |X|^2; track fp32 max; pack I*2^-12 to half2 regs ----
        #pragma unroll
        for (int q = 0; q < 8; ++q) {
            float I0 = x[2 * q].x     * x[2 * q].x     + x[2 * q].y     * x[2 * q].y;
            float I1 = x[2 * q + 1].x * x[2 * q + 1].x + x[2 * q + 1].y * x[2 * q + 1].y;
            mx = fmaxf(mx, fmaxf(I0, I1));
            hreg[r][q] = __floats2half2_rn(I0 * 0.000244140625f, I1 * 0.000244140625f);
        }
    }

    // ---- block-level max: wave shfl reduce -> LDS -> all threads ----
    #pragma unroll
    for (int off = 32; off; off >>= 1) mx = fmaxf(mx, __shfl_xor(mx, off, 64));
    if ((tid & 63) == 0) wmax[tid >> 6] = mx;
    __syncthreads();   // also fences T: safe to reuse it as scratch below
    float bm = wmax[0];
    #pragma unroll
    for (int w = 1; w < 16; ++w) bm = fmaxf(bm, wmax[w]);
    const float inv = 4096.0f / fmaxf(bm, EPS);   // undo 2^-12 and normalize

    // ---- epilogue: scatter into LDS row, read back contiguous, coalesced
    //      float4 global stores. fftshift both axes + reverse last axis. ----
    float* scratch = (float*)T;                 // 64 groups x stride 264 floats
    float* srow = scratch + G * 264;
    const int v = 127 - k1;
    #pragma unroll
    for (int r = 0; r < 4; ++r) {
        const int i = (r << 6) + G;
        const size_t rbase = ((size_t)b << 16) + ((size_t)(i ^ 128) << 8);
        #pragma unroll
        for (int q = 0; q < 8; ++q) {
            float2 f = __half22float2(hreg[r][q]);
            int k0  = (v - 16 * R4C(2 * q))     & 255;
            int k1o = (v - 16 * R4C(2 * q + 1)) & 255;
            srow[k0]  = f.x * inv;
            srow[k1o] = f.y * inv;
        }
        // group-private slice + same-wave lockstep: no barrier needed
        #pragma unroll
        for (int q = 0; q < 4; ++q) {
            int chunk = ((q + (l >> 1)) & 3) << 2;       // rotate: LDS 2-way max
            float4 vv = *(float4*)&srow[l * 16 + chunk];
            *(float4*)&out[rbase + l * 16 + chunk] = vv;
        }
    }
}

extern "C" void kernel_launch(void* const* d_in, const int* in_sizes, int n_in,
                              void* d_out, int out_size, void* d_ws, size_t ws_size,
                              hipStream_t stream) {
    const float* x = (const float*)d_in[0];
    float* out = (float*)d_out;
    k_fused<<<BB, 1024, 0, stream>>>(x, out);
}

// Round 3
// 208.481 us; speedup vs baseline: 1.1183x; 1.1183x over previous
//
#include <hip/hip_runtime.h>
#include <hip/hip_fp16.h>
#include <math.h>

#define EPS 1e-20f
#define NPT 256
#define BB  512

// ---- complex float2 helpers ----
__device__ __forceinline__ float2 cadd(float2 a, float2 b){ return make_float2(a.x+b.x, a.y+b.y); }
__device__ __forceinline__ float2 csub(float2 a, float2 b){ return make_float2(a.x-b.x, a.y-b.y); }
__device__ __forceinline__ float2 cmul(float2 a, float2 b){ return make_float2(a.x*b.x - a.y*b.y, a.x*b.y + a.y*b.x); }
__device__ __forceinline__ float2 cmulc(float2 a, float c, float s){ return make_float2(a.x*c - a.y*s, a.x*s + a.y*c); }
__device__ __forceinline__ float2 cmulmi(float2 a){ return make_float2(a.y, -a.x); }   // * (-i)

__device__ __forceinline__ void bfly4(float2& c0, float2& c1, float2& c2, float2& c3) {
    float2 s0 = cadd(c0, c2), s1 = cadd(c1, c3);
    float2 d0 = csub(c0, c2), d1 = cmulmi(csub(c1, c3));
    c0 = cadd(s0, s1); c1 = cadd(d0, d1); c2 = csub(s0, s1); c3 = csub(d0, d1);
}

#define C16_1 0.9238795325112867f
#define S16_1 (-0.3826834323650898f)
#define C16_2 0.7071067811865476f
#define S16_2 (-0.7071067811865476f)
#define C16_3 0.3826834323650898f
#define S16_3 (-0.9238795325112867f)
#define C16_6 (-0.7071067811865476f)
#define S16_6 (-0.7071067811865476f)
#define C16_9 (-0.9238795325112867f)
#define S16_9 0.3826834323650898f

// in-place 16-pt DIF DFT; position p ends up holding frequency r4(p)=4(p&3)+(p>>2)
__device__ __forceinline__ void dft16(float2* x) {
    bfly4(x[0], x[4], x[8], x[12]);
    bfly4(x[1], x[5], x[9], x[13]);
    x[5]  = cmulc(x[5],  C16_1, S16_1);
    x[9]  = cmulc(x[9],  C16_2, S16_2);
    x[13] = cmulc(x[13], C16_3, S16_3);
    bfly4(x[2], x[6], x[10], x[14]);
    x[6]  = cmulc(x[6],  C16_2, S16_2);
    x[10] = cmulmi(x[10]);
    x[14] = cmulc(x[14], C16_6, S16_6);
    bfly4(x[3], x[7], x[11], x[15]);
    x[7]  = cmulc(x[7],  C16_3, S16_3);
    x[11] = cmulc(x[11], C16_6, S16_6);
    x[15] = cmulc(x[15], C16_9, S16_9);
    bfly4(x[0],  x[1],  x[2],  x[3]);
    bfly4(x[4],  x[5],  x[6],  x[7]);
    bfly4(x[8],  x[9],  x[10], x[11]);
    bfly4(x[12], x[13], x[14], x[15]);
}

#define R4C(p) ((((p) & 3) << 2) | ((p) >> 2))

// ---------------- fused kernel: one block per batch ----------------
// 1024 threads = 64 groups of 16 lanes; each group does 4 rows (i values).
// LDS (86.5KB) limits residency to 1 block/CU = 4 waves/SIMD, so declare
// __launch_bounds__(1024, 4): VGPR cap 128, not 64 -> no scratch spill.
// (Round 1/2 spilled hreg/x at VGPR=64 -> ~200MB extra HBM write + ~100MB fetch.)
__global__ __launch_bounds__(1024, 4) void k_fused(const float* __restrict__ xin,
                                                   float* __restrict__ out) {
    __shared__ float2 El[256];
    __shared__ __align__(16) __half2 T[64 * 328];  // transpose buf; reused as epilogue scratch
    __shared__ float wmax[16];

    const int tid = threadIdx.x;
    const int G   = tid >> 4;         // 0..63
    const int l   = tid & 15;
    const int b   = blockIdx.x;

    // stage raw E (normalization cancels in I/max(I))
    if (tid < 256)
        El[tid] = make_float2(xin[b * 512 + tid], xin[b * 512 + 256 + tid]);
    __syncthreads();

    // twiddle W256^{k1*n2} register powers; k1 = r4(l) (loop-invariant)
    const int k1 = R4C(l);
    float sn, cs;
    __sincosf(-0.024543692606170259f * (float)k1, &sn, &cs);   // -2pi/256 * k1
    const float2 w1 = make_float2(cs, sn);
    const float2 w2 = cmul(w1, w1), w3 = cmul(w2, w1);
    const float2 w4 = cmul(w2, w2), w8 = cmul(w4, w4), w12 = cmul(w8, w4);

    __half2 hreg[4][8];               // I * 2^-12, packed pairs (p2=2q, 2q+1)
    float mx = 0.0f;

    #pragma unroll
    for (int r = 0; r < 4; ++r) {
        const int i = (r << 6) + G;   // row index 0..255

        float2 x[16];
        // ---- gate: x[n1] = E[16n1+l] * E[(16n1+l-i)&255] ----
        #pragma unroll
        for (int n1 = 0; n1 < 16; ++n1) {
            int j = 16 * n1 + l;
            x[n1] = cmul(El[j], El[(j - i) & 255]);
        }

        // ---- inner DFT over n1: x[p1] = Y[k1=r4(p1)][n2=l] ----
        dft16(x);

        // ---- transpose through LDS (half2), b128 writes ----
        {
            float4* wp = (float4*)&T[G * 328 + l * 20];
            #pragma unroll
            for (int q = 0; q < 4; ++q) {
                float4 pk;
                __half2* hp = (__half2*)&pk;
                hp[0] = __floats2half2_rn(x[4 * q + 0].x, x[4 * q + 0].y);
                hp[1] = __floats2half2_rn(x[4 * q + 1].x, x[4 * q + 1].y);
                hp[2] = __floats2half2_rn(x[4 * q + 2].x, x[4 * q + 2].y);
                hp[3] = __floats2half2_rn(x[4 * q + 3].x, x[4 * q + 3].y);
                wp[q] = pk;
            }
        }
        // same wave -> lockstep -> no barrier needed (group reads only its own slice)
        #pragma unroll
        for (int j = 0; j < 16; ++j) {
            x[j] = __half22float2(T[G * 328 + j * 20 + l]);
        }

        // ---- twiddle W256^{k1*n2} ----
        x[1]  = cmul(x[1],  w1);
        x[2]  = cmul(x[2],  w2);
        x[3]  = cmul(x[3],  w3);
        x[4]  = cmul(x[4],  w4);
        x[5]  = cmul(cmul(x[5],  w1), w4);
        x[6]  = cmul(cmul(x[6],  w2), w4);
        x[7]  = cmul(cmul(x[7],  w3), w4);
        x[8]  = cmul(x[8],  w8);
        x[9]  = cmul(cmul(x[9],  w1), w8);
        x[10] = cmul(cmul(x[10], w2), w8);
        x[11] = cmul(cmul(x[11], w3), w8);
        x[12] = cmul(x[12], w12);
        x[13] = cmul(cmul(x[13], w1), w12);
        x[14] = cmul(cmul(x[14], w2), w12);
        x[15] = cmul(cmul(x[15], w3), w12);

        // ---- outer DFT over n2: x[p2] = X[k1 + 16*r4(p2)] ----
        dft16(x);

        // ---- I = |X|^2; track fp32 max; pack I*2^-12 to half2 regs ----
        #pragma unroll
        for (int q = 0; q < 8; ++q) {
            float I0 = x[2 * q].x     * x[2 * q].x     + x[2 * q].y     * x[2 * q].y;
            float I1 = x[2 * q + 1].x * x[2 * q + 1].x + x[2 * q + 1].y * x[2 * q + 1].y;
            mx = fmaxf(mx, fmaxf(I0, I1));
            hreg[r][q] = __floats2half2_rn(I0 * 0.000244140625f, I1 * 0.000244140625f);
        }
    }

    // ---- block-level max: wave shfl reduce -> LDS -> all threads ----
    #pragma unroll
    for (int off = 32; off; off >>= 1) mx = fmaxf(mx, __shfl_xor(mx, off, 64));
    if ((tid & 63) == 0) wmax[tid >> 6] = mx;
    __syncthreads();   // also fences T: safe to reuse it as scratch below
    float bm = wmax[0];
    #pragma unroll
    for (int w = 1; w < 16; ++w) bm = fmaxf(bm, wmax[w]);
    const float inv = 4096.0f / fmaxf(bm, EPS);   // undo 2^-12 and normalize

    // ---- epilogue: scatter into LDS row, read back contiguous, coalesced
    //      float4 global stores. fftshift both axes + reverse last axis. ----
    float* scratch = (float*)T;                 // 64 groups x stride 264 floats
    float* srow = scratch + G * 264;
    const int v = 127 - k1;
    #pragma unroll
    for (int r = 0; r < 4; ++r) {
        const int i = (r << 6) + G;
        const size_t rbase = ((size_t)b << 16) + ((size_t)(i ^ 128) << 8);
        #pragma unroll
        for (int q = 0; q < 8; ++q) {
            float2 f = __half22float2(hreg[r][q]);
            int k0  = (v - 16 * R4C(2 * q))     & 255;
            int k1o = (v - 16 * R4C(2 * q + 1)) & 255;
            srow[k0]  = f.x * inv;
            srow[k1o] = f.y * inv;
        }
        // group-private slice + same-wave lockstep: no barrier needed.
        // contiguous read-back: each instr covers full 64B lines (4 lanes/line)
        #pragma unroll
        for (int q = 0; q < 4; ++q) {
            float4 vv = *(float4*)&srow[q * 64 + l * 4];
            *(float4*)&out[rbase + q * 64 + l * 4] = vv;
        }
    }
}

extern "C" void kernel_launch(void* const* d_in, const int* in_sizes, int n_in,
                              void* d_out, int out_size, void* d_ws, size_t ws_size,
                              hipStream_t stream) {
    const float* x = (const float*)d_in[0];
    float* out = (float*)d_out;
    k_fused<<<BB, 1024, 0, stream>>>(x, out);
}